// Round 16
// baseline (287.343 us; speedup 1.0000x reference)
//
#include <hip/hip_runtime.h>

typedef __bf16 bf16x8 __attribute__((ext_vector_type(8)));
typedef __bf16 bf16x4 __attribute__((ext_vector_type(4)));
typedef float  f32x4  __attribute__((ext_vector_type(4)));
typedef int    i32x4  __attribute__((ext_vector_type(4)));

typedef __attribute__((address_space(1))) unsigned int as1_u32;
typedef __attribute__((address_space(3))) unsigned int as3_u32;

#define DEVI __device__ __forceinline__

DEVI unsigned short f2bf(float f) {
    union { float f; unsigned u; } v; v.f = f;
    unsigned r = (v.u + 0x7fffu + ((v.u >> 16) & 1u)) >> 16;
    return (unsigned short)r;
}

// direct global->LDS 16B: lane L's 16B lands at ldsbase + L*16
DEVI void gload16(const void* g, void* l) {
    __builtin_amdgcn_global_load_lds((const as1_u32*)g, (as3_u32*)l, 16, 0, 0);
}

// softmax(x/8) = exp2(x * 0.125 * log2(e)); scale folded into Q projection.
#define C_EXP 0.18033688011112042f
// -10000 * log2(e)
#define MASK_ADD (-14426.950408889634f)

// ---------------------------------------------------------------------------
// Fused pre-pass (one launch):
//  blocks [0,2048):    f32->bf16 convert of value AND query (grid-stride)
//  blocks [2048,3072): 4x weight transpose W[k][n] -> WT[n][k]*scale
//  blocks [3072,5120): mask not-all-true BYTES (no atomics / no pre-zero)
// ---------------------------------------------------------------------------
__global__ __launch_bounds__(256) void prepass_kernel(const float* __restrict__ value,
                                                      unsigned short* __restrict__ VCONV,
                                                      const float* __restrict__ query,
                                                      unsigned short* __restrict__ QCONV,
                                                      const float* __restrict__ Wq,
                                                      const float* __restrict__ Wk,
                                                      const float* __restrict__ Wv,
                                                      const float* __restrict__ Wo,
                                                      unsigned short* __restrict__ WqT,
                                                      unsigned short* __restrict__ WkT,
                                                      unsigned short* __restrict__ WvT,
                                                      unsigned short* __restrict__ WoT,
                                                      const int* __restrict__ mask,
                                                      unsigned char* __restrict__ flagsB) {
    __shared__ float tile[64][65];
    const int bid = blockIdx.x;
    const int tid = threadIdx.x;

    if (bid < 2048) {
        const int n8 = 8192 * 1024 / 8;
        const int total = 2 * n8;
        for (int idx = bid * 256 + tid; idx < total; idx += 2048 * 256) {
            const int sel = idx >= n8;
            const int j = sel ? idx - n8 : idx;
            const float* in = sel ? query : value;
            unsigned short* out = sel ? QCONV : VCONV;
            const f32x4 a = *(const f32x4*)(in + (size_t)j * 8);
            const f32x4 b = *(const f32x4*)(in + (size_t)j * 8 + 4);
            union { bf16x4 v[2]; i32x4 q; } u;
            u.v[0] = __builtin_convertvector(a, bf16x4);
            u.v[1] = __builtin_convertvector(b, bf16x4);
            *(i32x4*)(out + (size_t)j * 8) = u.q;
        }
    } else if (bid < 3072) {
        const int e = bid - 2048;
        const int bx = e & 15, by = (e >> 4) & 15, z = e >> 8;
        const float* W;
        unsigned short* WT;
        float scale = 1.0f;
        switch (z) {
            case 0:  W = Wq; WT = WqT; scale = C_EXP; break;
            case 1:  W = Wk; WT = WkT; break;
            case 2:  W = Wv; WT = WvT; break;
            default: W = Wo; WT = WoT; break;
        }
        const int k0 = bx * 64, n0 = by * 64;
        const int c4 = (tid & 15) * 4, rbase = tid >> 4;
        for (int rr = 0; rr < 4; ++rr) {
            const int kl = rbase + rr * 16;
            const float4 v = *(const float4*)(W + (size_t)(k0 + kl) * 1024 + n0 + c4);
            tile[kl][c4 + 0] = v.x; tile[kl][c4 + 1] = v.y;
            tile[kl][c4 + 2] = v.z; tile[kl][c4 + 3] = v.w;
        }
        __syncthreads();
        for (int rr = 0; rr < 4; ++rr) {
            const int nl = rbase + rr * 16;
            ushort4 o;
            o.x = f2bf(tile[c4 + 0][nl] * scale); o.y = f2bf(tile[c4 + 1][nl] * scale);
            o.z = f2bf(tile[c4 + 2][nl] * scale); o.w = f2bf(tile[c4 + 3][nl] * scale);
            *(ushort4*)(WT + (size_t)(n0 + nl) * 1024 + k0 + c4) = o;
        }
    } else {
        const int e = bid - 3072;
        const int b = e >> 9, rem = e & 511;
        const int tb = rem >> 5, si = rem & 31;
        const int t = tb * 128 + (tid >> 1);
        const int s = si * 64 + (tid & 1) * 32;
        const uint4* p = (const uint4*)(mask + ((size_t)(b * 2048 + t)) * 2048 + s);
        int ok = 1;
        #pragma unroll
        for (int u = 0; u < 8; ++u) {
            const uint4 a = p[u];
            ok &= (a.x != 0) & (a.y != 0) & (a.z != 0) & (a.w != 0);
        }
        int all = __syncthreads_and(ok);
        if (tid == 0) flagsB[(b * 16 + tb) * 32 + si] = (unsigned char)(!all);
    }
}

// ---------------------------------------------------------------------------
// Unified bf16 GEMM (R10 loop): 128x128 tile, BK=64, double-buffered
// global_load_lds staging, XOR chunk-swizzle swz8(r)=(r^(r>>2))&7, XCD grid.
// MODE 0: bf16 Q-scatter   MODE 2: f32 linear   MODE 3: K|V   MODE 4: K|V|Q.
// ---------------------------------------------------------------------------
template <int MODE, int NB>
__global__ __launch_bounds__(256) void mm_kernel(const unsigned short* __restrict__ A0,
                                                 const unsigned short* __restrict__ A1,
                                                 const unsigned short* __restrict__ BT,
                                                 const float* __restrict__ biasK,
                                                 const float* __restrict__ biasV,
                                                 const float* __restrict__ biasQ,
                                                 float bscale,
                                                 void* __restrict__ OvK,
                                                 void* __restrict__ OvV,
                                                 void* __restrict__ OvQ) {
    __shared__ __align__(16) unsigned short Ab[2][128 * 64];
    __shared__ __align__(16) unsigned short Bb[2][128 * 64];
    const int bid = blockIdx.x;
    const int xcd = bid & 7, jj = bid >> 3;
    const int n0 = (jj % NB) * 128;
    const int m0 = ((jj / NB) * 8 + xcd) * 128;
    const int i = threadIdx.x, w = i >> 6, l = i & 63;
    const int wm = w >> 1, wn = w & 1;
    const int c = l & 15, g = l >> 4;
    const int srow = l >> 3, sslot = l & 7;

    const unsigned short* A = (MODE == 4 && n0 >= 2048) ? A1 : A0;

    f32x4 acc[4][4] = {};

    const unsigned short* As[4];
    const unsigned short* Bs[4];
    unsigned lofs[4];
    #pragma unroll
    for (int u = 0; u < 4; ++u) {
        const int rl = w * 32 + u * 8 + srow;
        const int ch = sslot ^ ((rl ^ (rl >> 2)) & 7);
        As[u] = A  + (size_t)(m0 + rl) * 1024 + ch * 8;
        Bs[u] = BT + (size_t)(n0 + rl) * 1024 + ch * 8;
        lofs[u] = (unsigned)((w * 32 + u * 8) * 64);
    }

    #pragma unroll
    for (int u = 0; u < 4; ++u) {
        gload16(As[u], &Ab[0][lofs[u]]);
        gload16(Bs[u], &Bb[0][lofs[u]]);
    }
    __syncthreads();

    int rsA[4], rsB[4];
    #pragma unroll
    for (int f = 0; f < 4; ++f) {
        const int ra = wm * 64 + f * 16 + c;
        const int rb = wn * 64 + f * 16 + c;
        rsA[f] = (ra ^ (ra >> 2)) & 7;
        rsB[f] = (rb ^ (rb >> 2)) & 7;
    }

    #pragma unroll 2
    for (int it = 0; it < 16; ++it) {
        const int buf = it & 1;
        if (it < 15) {
            #pragma unroll
            for (int u = 0; u < 4; ++u) {
                gload16(As[u] + (it + 1) * 64, &Ab[buf ^ 1][lofs[u]]);
                gload16(Bs[u] + (it + 1) * 64, &Bb[buf ^ 1][lofs[u]]);
            }
        }
        bf16x8 af[4][2], bfr[4][2];
        #pragma unroll
        for (int f = 0; f < 4; ++f)
            #pragma unroll
            for (int kk = 0; kk < 2; ++kk) {
                af[f][kk]  = *(const bf16x8*)&Ab[buf][(wm * 64 + f * 16 + c) * 64 + (((kk * 4 + g) ^ rsA[f]) * 8)];
                bfr[f][kk] = *(const bf16x8*)&Bb[buf][(wn * 64 + f * 16 + c) * 64 + (((kk * 4 + g) ^ rsB[f]) * 8)];
            }
        __builtin_amdgcn_s_setprio(1);
        #pragma unroll
        for (int kk = 0; kk < 2; ++kk)
            #pragma unroll
            for (int mf = 0; mf < 4; ++mf)
                #pragma unroll
                for (int nf = 0; nf < 4; ++nf)
                    acc[mf][nf] = __builtin_amdgcn_mfma_f32_16x16x32_bf16(af[mf][kk], bfr[nf][kk], acc[mf][nf], 0, 0, 0);
        __builtin_amdgcn_s_setprio(0);
        __syncthreads();
    }

    #pragma unroll
    for (int nf = 0; nf < 4; ++nf) {
        const int n = n0 + wn * 64 + nf * 16 + c;
        const bool isK = (MODE == 0) || ((MODE == 3 || MODE == 4) && n0 < 1024);
        const bool isV = (MODE == 3 || MODE == 4) && n0 >= 1024 && n0 < 2048;
        const bool isQ = (MODE == 4) && n0 >= 2048;
        if (isK) {
            const float bv = biasK[n] * bscale;
            const int h = n >> 6, cc = n & 63;
            unsigned short* O = (unsigned short*)OvK;
            #pragma unroll
            for (int mf = 0; mf < 4; ++mf) {
                const int mbase = m0 + wm * 64 + mf * 16 + g * 4;
                const int b = mbase >> 11, t = mbase & 2047;
                #pragma unroll
                for (int r = 0; r < 4; ++r)
                    O[(((size_t)(b * 16 + h)) * 2048 + t + r) * 64 + cc] = f2bf(acc[mf][nf][r] + bv);
            }
        } else if (isV) {
            const int nn = n - 1024;
            const float bv = biasV[nn];
            const int h = nn >> 6, cc = nn & 63;
            unsigned short* O = (unsigned short*)OvV;
            #pragma unroll
            for (int mf = 0; mf < 4; ++mf) {
                const int mbase = m0 + wm * 64 + mf * 16 + g * 4;
                const int b = mbase >> 11, t = mbase & 2047;
                f32x4 v;
                #pragma unroll
                for (int r = 0; r < 4; ++r) v[r] = acc[mf][nf][r] + bv;
                bf16x4 pv = __builtin_convertvector(v, bf16x4);
                *(bf16x4*)(O + (((size_t)(b * 16 + h)) * 64 + cc) * 2048 + t) = pv;
            }
        } else if (isQ) {
            const int nn = n - 2048;
            const float bv = biasQ[nn] * C_EXP;
            const int h = nn >> 6, cc = nn & 63;
            unsigned short* O = (unsigned short*)OvQ;
            #pragma unroll
            for (int mf = 0; mf < 4; ++mf) {
                const int mbase = m0 + wm * 64 + mf * 16 + g * 4;
                const int b = mbase >> 11, t = mbase & 2047;
                #pragma unroll
                for (int r = 0; r < 4; ++r)
                    O[(((size_t)(b * 16 + h)) * 2048 + t + r) * 64 + cc] = f2bf(acc[mf][nf][r] + bv);
            }
        } else {
            const float bv = biasK[n] * bscale;
            float* O = (float*)OvK;
            #pragma unroll
            for (int mf = 0; mf < 4; ++mf) {
                const int mbase = m0 + wm * 64 + mf * 16 + g * 4;
                #pragma unroll
                for (int r = 0; r < 4; ++r)
                    O[(size_t)(mbase + r) * 1024 + n] = acc[mf][nf][r] + bv;
            }
        }
    }
}

// ---------------------------------------------------------------------------
// Flash attention: swapped QK^T, permuted K rows, K32 PV, two 16-row t-groups.
// R16 change: exp2(B) moved OFF the critical path - per iter:
//   QK(A+B) -> mask -> exp2+pack(A) -> PV(A)+dacc(A) -> exp2+pack(B)
//   -> PV(B)+dacc(B) -> barrier.
// PV(B) re-reads vf from LDS (+8 ds_read_b128, underutilized pipe) to keep
// VGPR pressure flat. Everything else identical to R15.
// ---------------------------------------------------------------------------
__global__ __launch_bounds__(256, 4) void attn_kernel(const unsigned short* __restrict__ Qp,
                                                      const unsigned short* __restrict__ Kp,
                                                      const unsigned short* __restrict__ VTp,
                                                      const int* __restrict__ mask,
                                                      const unsigned char* __restrict__ flagsB,
                                                      unsigned short* __restrict__ attnb) {
    __shared__ __align__(16) unsigned short Kt[2][64 * 64];
    __shared__ __align__(16) unsigned short Vt[2][64 * 64];

    const int bid = blockIdx.x;
    const int xcd = bid & 7, jj = bid >> 3;
    const int bh = xcd * 8 + (jj >> 4);
    const int tb = jj & 15;
    const int b = bh >> 4, h = bh & 15;
    const int i = threadIdx.x, w = i >> 6, l = i & 63;
    const int c = l & 15, g = l >> 4;

    const unsigned short* Qb  = Qp  + (size_t)bh * 2048 * 64;
    const unsigned short* Kb  = Kp  + (size_t)bh * 2048 * 64;
    const unsigned short* VTb = VTp + (size_t)bh * 64 * 2048;

    const int twave = tb * 128 + w * 32;
    const int tA = twave + c, tB = twave + 16 + c;

    const unsigned char myb = flagsB[(size_t)(b * 16 + tb) * 32 + (l & 31)];
    const unsigned notall = (unsigned)__ballot(myb != 0);

    bf16x8 qfA[2], qfB[2];
    #pragma unroll
    for (int kq = 0; kq < 2; ++kq) {
        qfA[kq] = *(const bf16x8*)(Qb + (size_t)tA * 64 + kq * 32 + g * 8);
        qfB[kq] = *(const bf16x8*)(Qb + (size_t)tB * 64 + kq * 32 + g * 8);
    }

    f32x4 oA[4] = {}, oB[4] = {};
    f32x4 daccA = {}, daccB = {};
    const f32x4 zf = {};

    bf16x8 ones8;
    #pragma unroll
    for (int j = 0; j < 8; ++j) ones8[j] = (__bf16)1.0f;

    int rrow[4], rswz[4];
    #pragma unroll
    for (int sm = 0; sm < 4; ++sm) {
        rrow[sm] = (sm >> 1) * 32 + (c >> 2) * 8 + (sm & 1) * 4 + (c & 3);
        rswz[sm] = (rrow[sm] ^ (rrow[sm] >> 2)) & 7;
    }
    int vswz[4];
    #pragma unroll
    for (int vm = 0; vm < 4; ++vm) {
        const int rv = vm * 16 + c;
        vswz[vm] = (rv ^ (rv >> 2)) & 7;
    }

    const int srow = l >> 3, sslot = l & 7;

    const unsigned short* kstage[2];
    const unsigned short* vstage[2];
    #pragma unroll
    for (int u = 0; u < 2; ++u) {
        const int row = w * 16 + u * 8 + srow;
        const int ch = sslot ^ ((row ^ (row >> 2)) & 7);
        gload16(Kb + (size_t)row * 64 + ch * 8, &Kt[0][(w * 16 + u * 8) * 64]);
        gload16(VTb + (size_t)row * 2048 + ch * 8, &Vt[0][(w * 16 + u * 8) * 64]);
        kstage[u] = Kb + (size_t)(64 + row) * 64 + ch * 8;
        vstage[u] = VTb + (size_t)row * 2048 + 64 + ch * 8;
    }
    __syncthreads();

    #pragma unroll 2
    for (int it = 0; it < 32; ++it) {
        const int buf = it & 1;
        const int s0 = it * 64;

        if (it < 31) {
            #pragma unroll
            for (int u = 0; u < 2; ++u) {
                gload16(kstage[u], &Kt[buf ^ 1][(w * 16 + u * 8) * 64]);
                gload16(vstage[u], &Vt[buf ^ 1][(w * 16 + u * 8) * 64]);
                kstage[u] += 64 * 64;
                vstage[u] += 64;
            }
        }

        // QK^T for both groups (shared kf fragments)
        f32x4 scA[4], scB[4];
        __builtin_amdgcn_s_setprio(1);
        #pragma unroll
        for (int sm = 0; sm < 4; ++sm) {
            #pragma unroll
            for (int kq = 0; kq < 2; ++kq) {
                const bf16x8 kf = *(const bf16x8*)&Kt[buf][rrow[sm] * 64 + (((kq * 4 + g) ^ rswz[sm]) * 8)];
                if (kq == 0) {
                    scA[sm] = __builtin_amdgcn_mfma_f32_16x16x32_bf16(kf, qfA[0], zf, 0, 0, 0);
                    scB[sm] = __builtin_amdgcn_mfma_f32_16x16x32_bf16(kf, qfB[0], zf, 0, 0, 0);
                } else {
                    scA[sm] = __builtin_amdgcn_mfma_f32_16x16x32_bf16(kf, qfA[1], scA[sm], 0, 0, 0);
                    scB[sm] = __builtin_amdgcn_mfma_f32_16x16x32_bf16(kf, qfB[1], scB[sm], 0, 0, 0);
                }
            }
        }
        __builtin_amdgcn_s_setprio(0);

        if (notall & (1u << it)) {
            #pragma unroll
            for (int sm = 0; sm < 4; ++sm)
                #pragma unroll
                for (int r = 0; r < 4; ++r) {
                    const int s = s0 + (sm >> 1) * 32 + g * 8 + (sm & 1) * 4 + r;
                    if (mask[(size_t)(b * 2048 + tA) * 2048 + s] == 0) scA[sm][r] += MASK_ADD;
                    if (mask[(size_t)(b * 2048 + tB) * 2048 + s] == 0) scB[sm][r] += MASK_ADD;
                }
        }

        // exp2 + pack group A only
        bf16x8 paA[2];
        #pragma unroll
        for (int kv = 0; kv < 2; ++kv) {
            f32x4 a0, a1;
            #pragma unroll
            for (int r = 0; r < 4; ++r) {
                a0[r] = __builtin_amdgcn_exp2f(scA[kv * 2][r]);
                a1[r] = __builtin_amdgcn_exp2f(scA[kv * 2 + 1][r]);
            }
            union { struct { bf16x4 lo, hi; } hh; bf16x8 v; } ua;
            ua.hh.lo = __builtin_convertvector(a0, bf16x4);
            ua.hh.hi = __builtin_convertvector(a1, bf16x4);
            paA[kv] = ua.v;
        }

        // PV(A) + dacc(A)  (exp2(B) below is independent -> fills MFMA shadow)
        __builtin_amdgcn_s_setprio(1);
        #pragma unroll
        for (int kv = 0; kv < 2; ++kv) {
            daccA = __builtin_amdgcn_mfma_f32_16x16x32_bf16(ones8, paA[kv], daccA, 0, 0, 0);
            #pragma unroll
            for (int vm = 0; vm < 4; ++vm) {
                const bf16x8 vf = *(const bf16x8*)&Vt[buf][(vm * 16 + c) * 64 + (((kv * 4 + g) ^ vswz[vm]) * 8)];
                oA[vm] = __builtin_amdgcn_mfma_f32_16x16x32_bf16(vf, paA[kv], oA[vm], 0, 0, 0);
            }
        }
        __builtin_amdgcn_s_setprio(0);

        // exp2 + pack group B (overlaps PV(A) MFMAs)
        bf16x8 paB[2];
        #pragma unroll
        for (int kv = 0; kv < 2; ++kv) {
            f32x4 b0, b1;
            #pragma unroll
            for (int r = 0; r < 4; ++r) {
                b0[r] = __builtin_amdgcn_exp2f(scB[kv * 2][r]);
                b1[r] = __builtin_amdgcn_exp2f(scB[kv * 2 + 1][r]);
            }
            union { struct { bf16x4 lo, hi; } hh; bf16x8 v; } ub;
            ub.hh.lo = __builtin_convertvector(b0, bf16x4);
            ub.hh.hi = __builtin_convertvector(b1, bf16x4);
            paB[kv] = ub.v;
        }

        // PV(B) + dacc(B)  (vf re-read from LDS; pipe has slack)
        __builtin_amdgcn_s_setprio(1);
        #pragma unroll
        for (int kv = 0; kv < 2; ++kv) {
            daccB = __builtin_amdgcn_mfma_f32_16x16x32_bf16(ones8, paB[kv], daccB, 0, 0, 0);
            #pragma unroll
            for (int vm = 0; vm < 4; ++vm) {
                const bf16x8 vf = *(const bf16x8*)&Vt[buf][(vm * 16 + c) * 64 + (((kv * 4 + g) ^ vswz[vm]) * 8)];
                oB[vm] = __builtin_amdgcn_mfma_f32_16x16x32_bf16(vf, paB[kv], oB[vm], 0, 0, 0);
            }
        }
        __builtin_amdgcn_s_setprio(0);

        __syncthreads();
    }

    const float invA = 1.0f / daccA[0];
    const float invB = 1.0f / daccB[0];

    #pragma unroll
    for (int vm = 0; vm < 4; ++vm) {
        f32x4 vA, vB;
        #pragma unroll
        for (int r = 0; r < 4; ++r) { vA[r] = oA[vm][r] * invA; vB[r] = oB[vm][r] * invB; }
        bf16x4 pA = __builtin_convertvector(vA, bf16x4);
        bf16x4 pB = __builtin_convertvector(vB, bf16x4);
        *(bf16x4*)(attnb + (size_t)(b * 2048 + tA) * 1024 + h * 64 + vm * 16 + g * 4) = pA;
        *(bf16x4*)(attnb + (size_t)(b * 2048 + tB) * 1024 + h * 64 + vm * 16 + g * 4) = pB;
    }
}

// ---------------------------------------------------------------------------
extern "C" void kernel_launch(void* const* d_in, const int* in_sizes, int n_in,
                              void* d_out, int out_size, void* d_ws, size_t ws_size,
                              hipStream_t stream) {
    const float* query = (const float*)d_in[0];
    const float* value = (const float*)d_in[1];
    const int*   mask  = (const int*)d_in[2];
    const float* Wq = (const float*)d_in[3];
    const float* bq = (const float*)d_in[4];
    const float* Wk = (const float*)d_in[5];
    const float* bk = (const float*)d_in[6];
    const float* Wv = (const float*)d_in[7];
    const float* bv = (const float*)d_in[8];
    const float* Wo = (const float*)d_in[9];
    const float* bo = (const float*)d_in[10];

    char* ws = (char*)d_ws;
    unsigned short* WkT   = (unsigned short*)(ws + ((size_t)0  << 20));
    unsigned short* WvT   = (unsigned short*)(ws + ((size_t)2  << 20));
    unsigned short* WqT   = (unsigned short*)(ws + ((size_t)4  << 20));
    unsigned short* WoT   = (unsigned short*)(ws + ((size_t)6  << 20));
    unsigned char*  flagsB= (unsigned char*) (ws + ((size_t)8  << 20));
    unsigned short* VCONV = (unsigned short*)(ws + ((size_t)9  << 20));
    unsigned short* QCONV = (unsigned short*)(ws + ((size_t)25 << 20));
    unsigned short* Kp    = (unsigned short*)(ws + ((size_t)41 << 20));
    unsigned short* VTp   = (unsigned short*)(ws + ((size_t)57 << 20));

    const bool merged = ws_size >= ((size_t)90 << 20);
    unsigned short* Qp    = merged ? (unsigned short*)(ws + ((size_t)73 << 20)) : VCONV;
    unsigned short* attnb = QCONV;

    prepass_kernel<<<5120, 256, 0, stream>>>(value, VCONV, query, QCONV,
                                             Wq, Wk, Wv, Wo, WqT, WkT, WvT, WoT,
                                             mask, flagsB);

    if (merged) {
        mm_kernel<4, 24><<<1536, 256, 0, stream>>>(VCONV, QCONV, WkT, bk, bv, bq,
                                                   1.0f, Kp, VTp, Qp);
    } else {
        mm_kernel<3, 16><<<1024, 256, 0, stream>>>(VCONV, nullptr, WkT, bk, bv, bq,
                                                   1.0f, Kp, VTp, nullptr);
        mm_kernel<0, 8><<<512, 256, 0, stream>>>(QCONV, nullptr, WqT, bq, bq, bq,
                                                 C_EXP, Qp, nullptr, nullptr);
    }

    attn_kernel<<<1024, 256, 0, stream>>>(Qp, Kp, VTp, mask, flagsB, attnb);

    mm_kernel<2, 8><<<512, 256, 0, stream>>>(attnb, nullptr, WoT, bo, bo, bo,
                                             1.0f, d_out, nullptr, nullptr);
}

// Round 17
// 192.634 us; speedup vs baseline: 1.4916x; 1.4916x over previous
//
#include <hip/hip_runtime.h>

typedef __bf16 bf16x8 __attribute__((ext_vector_type(8)));
typedef __bf16 bf16x4 __attribute__((ext_vector_type(4)));
typedef float  f32x4  __attribute__((ext_vector_type(4)));
typedef int    i32x4  __attribute__((ext_vector_type(4)));

typedef __attribute__((address_space(1))) unsigned int as1_u32;
typedef __attribute__((address_space(3))) unsigned int as3_u32;

#define DEVI __device__ __forceinline__

DEVI unsigned short f2bf(float f) {
    union { float f; unsigned u; } v; v.f = f;
    unsigned r = (v.u + 0x7fffu + ((v.u >> 16) & 1u)) >> 16;
    return (unsigned short)r;
}

// direct global->LDS 16B: lane L's 16B lands at ldsbase + L*16
DEVI void gload16(const void* g, void* l) {
    __builtin_amdgcn_global_load_lds((const as1_u32*)g, (as3_u32*)l, 16, 0, 0);
}

// softmax(x/8) = exp2(x * 0.125 * log2(e)); scale folded into Q projection.
#define C_EXP 0.18033688011112042f
// -10000 * log2(e)
#define MASK_ADD (-14426.950408889634f)

// ---------------------------------------------------------------------------
// Fused pre-pass (one launch):
//  blocks [0,2048):    f32->bf16 convert of value AND query (grid-stride)
//  blocks [2048,3072): 4x weight transpose W[k][n] -> WT[n][k]*scale
//  blocks [3072,5120): mask not-all-true BYTES (no atomics / no pre-zero)
// ---------------------------------------------------------------------------
__global__ __launch_bounds__(256) void prepass_kernel(const float* __restrict__ value,
                                                      unsigned short* __restrict__ VCONV,
                                                      const float* __restrict__ query,
                                                      unsigned short* __restrict__ QCONV,
                                                      const float* __restrict__ Wq,
                                                      const float* __restrict__ Wk,
                                                      const float* __restrict__ Wv,
                                                      const float* __restrict__ Wo,
                                                      unsigned short* __restrict__ WqT,
                                                      unsigned short* __restrict__ WkT,
                                                      unsigned short* __restrict__ WvT,
                                                      unsigned short* __restrict__ WoT,
                                                      const int* __restrict__ mask,
                                                      unsigned char* __restrict__ flagsB) {
    __shared__ float tile[64][65];
    const int bid = blockIdx.x;
    const int tid = threadIdx.x;

    if (bid < 2048) {
        const int n8 = 8192 * 1024 / 8;
        const int total = 2 * n8;
        for (int idx = bid * 256 + tid; idx < total; idx += 2048 * 256) {
            const int sel = idx >= n8;
            const int j = sel ? idx - n8 : idx;
            const float* in = sel ? query : value;
            unsigned short* out = sel ? QCONV : VCONV;
            const f32x4 a = *(const f32x4*)(in + (size_t)j * 8);
            const f32x4 b = *(const f32x4*)(in + (size_t)j * 8 + 4);
            union { bf16x4 v[2]; i32x4 q; } u;
            u.v[0] = __builtin_convertvector(a, bf16x4);
            u.v[1] = __builtin_convertvector(b, bf16x4);
            *(i32x4*)(out + (size_t)j * 8) = u.q;
        }
    } else if (bid < 3072) {
        const int e = bid - 2048;
        const int bx = e & 15, by = (e >> 4) & 15, z = e >> 8;
        const float* W;
        unsigned short* WT;
        float scale = 1.0f;
        switch (z) {
            case 0:  W = Wq; WT = WqT; scale = C_EXP; break;
            case 1:  W = Wk; WT = WkT; break;
            case 2:  W = Wv; WT = WvT; break;
            default: W = Wo; WT = WoT; break;
        }
        const int k0 = bx * 64, n0 = by * 64;
        const int c4 = (tid & 15) * 4, rbase = tid >> 4;
        for (int rr = 0; rr < 4; ++rr) {
            const int kl = rbase + rr * 16;
            const float4 v = *(const float4*)(W + (size_t)(k0 + kl) * 1024 + n0 + c4);
            tile[kl][c4 + 0] = v.x; tile[kl][c4 + 1] = v.y;
            tile[kl][c4 + 2] = v.z; tile[kl][c4 + 3] = v.w;
        }
        __syncthreads();
        for (int rr = 0; rr < 4; ++rr) {
            const int nl = rbase + rr * 16;
            ushort4 o;
            o.x = f2bf(tile[c4 + 0][nl] * scale); o.y = f2bf(tile[c4 + 1][nl] * scale);
            o.z = f2bf(tile[c4 + 2][nl] * scale); o.w = f2bf(tile[c4 + 3][nl] * scale);
            *(ushort4*)(WT + (size_t)(n0 + nl) * 1024 + k0 + c4) = o;
        }
    } else {
        const int e = bid - 3072;
        const int b = e >> 9, rem = e & 511;
        const int tb = rem >> 5, si = rem & 31;
        const int t = tb * 128 + (tid >> 1);
        const int s = si * 64 + (tid & 1) * 32;
        const uint4* p = (const uint4*)(mask + ((size_t)(b * 2048 + t)) * 2048 + s);
        int ok = 1;
        #pragma unroll
        for (int u = 0; u < 8; ++u) {
            const uint4 a = p[u];
            ok &= (a.x != 0) & (a.y != 0) & (a.z != 0) & (a.w != 0);
        }
        int all = __syncthreads_and(ok);
        if (tid == 0) flagsB[(b * 16 + tb) * 32 + si] = (unsigned char)(!all);
    }
}

// ---------------------------------------------------------------------------
// Unified bf16 GEMM (R10 loop): 128x128 tile, BK=64, double-buffered
// global_load_lds staging, XOR chunk-swizzle swz8(r)=(r^(r>>2))&7, XCD grid.
// MODE 0: bf16 Q-scatter   MODE 2: f32 linear   MODE 3: K|V   MODE 4: K|V|Q.
// ---------------------------------------------------------------------------
template <int MODE, int NB>
__global__ __launch_bounds__(256) void mm_kernel(const unsigned short* __restrict__ A0,
                                                 const unsigned short* __restrict__ A1,
                                                 const unsigned short* __restrict__ BT,
                                                 const float* __restrict__ biasK,
                                                 const float* __restrict__ biasV,
                                                 const float* __restrict__ biasQ,
                                                 float bscale,
                                                 void* __restrict__ OvK,
                                                 void* __restrict__ OvV,
                                                 void* __restrict__ OvQ) {
    __shared__ __align__(16) unsigned short Ab[2][128 * 64];
    __shared__ __align__(16) unsigned short Bb[2][128 * 64];
    const int bid = blockIdx.x;
    const int xcd = bid & 7, jj = bid >> 3;
    const int n0 = (jj % NB) * 128;
    const int m0 = ((jj / NB) * 8 + xcd) * 128;
    const int i = threadIdx.x, w = i >> 6, l = i & 63;
    const int wm = w >> 1, wn = w & 1;
    const int c = l & 15, g = l >> 4;
    const int srow = l >> 3, sslot = l & 7;

    const unsigned short* A = (MODE == 4 && n0 >= 2048) ? A1 : A0;

    f32x4 acc[4][4] = {};

    const unsigned short* As[4];
    const unsigned short* Bs[4];
    unsigned lofs[4];
    #pragma unroll
    for (int u = 0; u < 4; ++u) {
        const int rl = w * 32 + u * 8 + srow;
        const int ch = sslot ^ ((rl ^ (rl >> 2)) & 7);
        As[u] = A  + (size_t)(m0 + rl) * 1024 + ch * 8;
        Bs[u] = BT + (size_t)(n0 + rl) * 1024 + ch * 8;
        lofs[u] = (unsigned)((w * 32 + u * 8) * 64);
    }

    #pragma unroll
    for (int u = 0; u < 4; ++u) {
        gload16(As[u], &Ab[0][lofs[u]]);
        gload16(Bs[u], &Bb[0][lofs[u]]);
    }
    __syncthreads();

    int rsA[4], rsB[4];
    #pragma unroll
    for (int f = 0; f < 4; ++f) {
        const int ra = wm * 64 + f * 16 + c;
        const int rb = wn * 64 + f * 16 + c;
        rsA[f] = (ra ^ (ra >> 2)) & 7;
        rsB[f] = (rb ^ (rb >> 2)) & 7;
    }

    #pragma unroll 2
    for (int it = 0; it < 16; ++it) {
        const int buf = it & 1;
        if (it < 15) {
            #pragma unroll
            for (int u = 0; u < 4; ++u) {
                gload16(As[u] + (it + 1) * 64, &Ab[buf ^ 1][lofs[u]]);
                gload16(Bs[u] + (it + 1) * 64, &Bb[buf ^ 1][lofs[u]]);
            }
        }
        bf16x8 af[4][2], bfr[4][2];
        #pragma unroll
        for (int f = 0; f < 4; ++f)
            #pragma unroll
            for (int kk = 0; kk < 2; ++kk) {
                af[f][kk]  = *(const bf16x8*)&Ab[buf][(wm * 64 + f * 16 + c) * 64 + (((kk * 4 + g) ^ rsA[f]) * 8)];
                bfr[f][kk] = *(const bf16x8*)&Bb[buf][(wn * 64 + f * 16 + c) * 64 + (((kk * 4 + g) ^ rsB[f]) * 8)];
            }
        __builtin_amdgcn_s_setprio(1);
        #pragma unroll
        for (int kk = 0; kk < 2; ++kk)
            #pragma unroll
            for (int mf = 0; mf < 4; ++mf)
                #pragma unroll
                for (int nf = 0; nf < 4; ++nf)
                    acc[mf][nf] = __builtin_amdgcn_mfma_f32_16x16x32_bf16(af[mf][kk], bfr[nf][kk], acc[mf][nf], 0, 0, 0);
        __builtin_amdgcn_s_setprio(0);
        __syncthreads();
    }

    #pragma unroll
    for (int nf = 0; nf < 4; ++nf) {
        const int n = n0 + wn * 64 + nf * 16 + c;
        const bool isK = (MODE == 0) || ((MODE == 3 || MODE == 4) && n0 < 1024);
        const bool isV = (MODE == 3 || MODE == 4) && n0 >= 1024 && n0 < 2048;
        const bool isQ = (MODE == 4) && n0 >= 2048;
        if (isK) {
            const float bv = biasK[n] * bscale;
            const int h = n >> 6, cc = n & 63;
            unsigned short* O = (unsigned short*)OvK;
            #pragma unroll
            for (int mf = 0; mf < 4; ++mf) {
                const int mbase = m0 + wm * 64 + mf * 16 + g * 4;
                const int b = mbase >> 11, t = mbase & 2047;
                #pragma unroll
                for (int r = 0; r < 4; ++r)
                    O[(((size_t)(b * 16 + h)) * 2048 + t + r) * 64 + cc] = f2bf(acc[mf][nf][r] + bv);
            }
        } else if (isV) {
            const int nn = n - 1024;
            const float bv = biasV[nn];
            const int h = nn >> 6, cc = nn & 63;
            unsigned short* O = (unsigned short*)OvV;
            #pragma unroll
            for (int mf = 0; mf < 4; ++mf) {
                const int mbase = m0 + wm * 64 + mf * 16 + g * 4;
                const int b = mbase >> 11, t = mbase & 2047;
                f32x4 v;
                #pragma unroll
                for (int r = 0; r < 4; ++r) v[r] = acc[mf][nf][r] + bv;
                bf16x4 pv = __builtin_convertvector(v, bf16x4);
                *(bf16x4*)(O + (((size_t)(b * 16 + h)) * 64 + cc) * 2048 + t) = pv;
            }
        } else if (isQ) {
            const int nn = n - 2048;
            const float bv = biasQ[nn] * C_EXP;
            const int h = nn >> 6, cc = nn & 63;
            unsigned short* O = (unsigned short*)OvQ;
            #pragma unroll
            for (int mf = 0; mf < 4; ++mf) {
                const int mbase = m0 + wm * 64 + mf * 16 + g * 4;
                const int b = mbase >> 11, t = mbase & 2047;
                #pragma unroll
                for (int r = 0; r < 4; ++r)
                    O[(((size_t)(b * 16 + h)) * 2048 + t + r) * 64 + cc] = f2bf(acc[mf][nf][r] + bv);
            }
        } else {
            const float bv = biasK[n] * bscale;
            float* O = (float*)OvK;
            #pragma unroll
            for (int mf = 0; mf < 4; ++mf) {
                const int mbase = m0 + wm * 64 + mf * 16 + g * 4;
                #pragma unroll
                for (int r = 0; r < 4; ++r)
                    O[(size_t)(mbase + r) * 1024 + n] = acc[mf][nf][r] + bv;
            }
        }
    }
}

// ---------------------------------------------------------------------------
// Flash attention (R15 proven loop): swapped QK^T, permuted K rows, K32 PV,
// two 16-row t-groups per wave, grid 1024 (4 blocks/CU), XOR swizzle, XCD map.
// Flags BYTES: bitword rebuilt via one byte-load/lane + __ballot.
// ---------------------------------------------------------------------------
__global__ __launch_bounds__(256, 4) void attn_kernel(const unsigned short* __restrict__ Qp,
                                                      const unsigned short* __restrict__ Kp,
                                                      const unsigned short* __restrict__ VTp,
                                                      const int* __restrict__ mask,
                                                      const unsigned char* __restrict__ flagsB,
                                                      unsigned short* __restrict__ attnb) {
    __shared__ __align__(16) unsigned short Kt[2][64 * 64];
    __shared__ __align__(16) unsigned short Vt[2][64 * 64];

    const int bid = blockIdx.x;
    const int xcd = bid & 7, jj = bid >> 3;
    const int bh = xcd * 8 + (jj >> 4);
    const int tb = jj & 15;
    const int b = bh >> 4, h = bh & 15;
    const int i = threadIdx.x, w = i >> 6, l = i & 63;
    const int c = l & 15, g = l >> 4;

    const unsigned short* Qb  = Qp  + (size_t)bh * 2048 * 64;
    const unsigned short* Kb  = Kp  + (size_t)bh * 2048 * 64;
    const unsigned short* VTb = VTp + (size_t)bh * 64 * 2048;

    const int twave = tb * 128 + w * 32;
    const int tA = twave + c, tB = twave + 16 + c;

    const unsigned char myb = flagsB[(size_t)(b * 16 + tb) * 32 + (l & 31)];
    const unsigned notall = (unsigned)__ballot(myb != 0);

    bf16x8 qfA[2], qfB[2];
    #pragma unroll
    for (int kq = 0; kq < 2; ++kq) {
        qfA[kq] = *(const bf16x8*)(Qb + (size_t)tA * 64 + kq * 32 + g * 8);
        qfB[kq] = *(const bf16x8*)(Qb + (size_t)tB * 64 + kq * 32 + g * 8);
    }

    f32x4 oA[4] = {}, oB[4] = {};
    f32x4 daccA = {}, daccB = {};
    const f32x4 zf = {};

    bf16x8 ones8;
    #pragma unroll
    for (int j = 0; j < 8; ++j) ones8[j] = (__bf16)1.0f;

    int rrow[4], rswz[4];
    #pragma unroll
    for (int sm = 0; sm < 4; ++sm) {
        rrow[sm] = (sm >> 1) * 32 + (c >> 2) * 8 + (sm & 1) * 4 + (c & 3);
        rswz[sm] = (rrow[sm] ^ (rrow[sm] >> 2)) & 7;
    }
    int vswz[4];
    #pragma unroll
    for (int vm = 0; vm < 4; ++vm) {
        const int rv = vm * 16 + c;
        vswz[vm] = (rv ^ (rv >> 2)) & 7;
    }

    const int srow = l >> 3, sslot = l & 7;

    const unsigned short* kstage[2];
    const unsigned short* vstage[2];
    #pragma unroll
    for (int u = 0; u < 2; ++u) {
        const int row = w * 16 + u * 8 + srow;
        const int ch = sslot ^ ((row ^ (row >> 2)) & 7);
        gload16(Kb + (size_t)row * 64 + ch * 8, &Kt[0][(w * 16 + u * 8) * 64]);
        gload16(VTb + (size_t)row * 2048 + ch * 8, &Vt[0][(w * 16 + u * 8) * 64]);
        kstage[u] = Kb + (size_t)(64 + row) * 64 + ch * 8;
        vstage[u] = VTb + (size_t)row * 2048 + 64 + ch * 8;
    }
    __syncthreads();

    #pragma unroll 2
    for (int it = 0; it < 32; ++it) {
        const int buf = it & 1;
        const int s0 = it * 64;

        if (it < 31) {
            #pragma unroll
            for (int u = 0; u < 2; ++u) {
                gload16(kstage[u], &Kt[buf ^ 1][(w * 16 + u * 8) * 64]);
                gload16(vstage[u], &Vt[buf ^ 1][(w * 16 + u * 8) * 64]);
                kstage[u] += 64 * 64;
                vstage[u] += 64;
            }
        }

        f32x4 scA[4], scB[4];
        __builtin_amdgcn_s_setprio(1);
        #pragma unroll
        for (int sm = 0; sm < 4; ++sm) {
            #pragma unroll
            for (int kq = 0; kq < 2; ++kq) {
                const bf16x8 kf = *(const bf16x8*)&Kt[buf][rrow[sm] * 64 + (((kq * 4 + g) ^ rswz[sm]) * 8)];
                if (kq == 0) {
                    scA[sm] = __builtin_amdgcn_mfma_f32_16x16x32_bf16(kf, qfA[0], zf, 0, 0, 0);
                    scB[sm] = __builtin_amdgcn_mfma_f32_16x16x32_bf16(kf, qfB[0], zf, 0, 0, 0);
                } else {
                    scA[sm] = __builtin_amdgcn_mfma_f32_16x16x32_bf16(kf, qfA[1], scA[sm], 0, 0, 0);
                    scB[sm] = __builtin_amdgcn_mfma_f32_16x16x32_bf16(kf, qfB[1], scB[sm], 0, 0, 0);
                }
            }
        }
        __builtin_amdgcn_s_setprio(0);

        if (notall & (1u << it)) {
            #pragma unroll
            for (int sm = 0; sm < 4; ++sm)
                #pragma unroll
                for (int r = 0; r < 4; ++r) {
                    const int s = s0 + (sm >> 1) * 32 + g * 8 + (sm & 1) * 4 + r;
                    if (mask[(size_t)(b * 2048 + tA) * 2048 + s] == 0) scA[sm][r] += MASK_ADD;
                    if (mask[(size_t)(b * 2048 + tB) * 2048 + s] == 0) scB[sm][r] += MASK_ADD;
                }
        }

        bf16x8 paA[2], paB[2];
        #pragma unroll
        for (int kv = 0; kv < 2; ++kv) {
            f32x4 a0, a1, b0, b1;
            #pragma unroll
            for (int r = 0; r < 4; ++r) {
                a0[r] = __builtin_amdgcn_exp2f(scA[kv * 2][r]);
                a1[r] = __builtin_amdgcn_exp2f(scA[kv * 2 + 1][r]);
                b0[r] = __builtin_amdgcn_exp2f(scB[kv * 2][r]);
                b1[r] = __builtin_amdgcn_exp2f(scB[kv * 2 + 1][r]);
            }
            union { struct { bf16x4 lo, hi; } hh; bf16x8 v; } ua, ub;
            ua.hh.lo = __builtin_convertvector(a0, bf16x4);
            ua.hh.hi = __builtin_convertvector(a1, bf16x4);
            ub.hh.lo = __builtin_convertvector(b0, bf16x4);
            ub.hh.hi = __builtin_convertvector(b1, bf16x4);
            paA[kv] = ua.v;
            paB[kv] = ub.v;
        }

        __builtin_amdgcn_s_setprio(1);
        #pragma unroll
        for (int kv = 0; kv < 2; ++kv) {
            daccA = __builtin_amdgcn_mfma_f32_16x16x32_bf16(ones8, paA[kv], daccA, 0, 0, 0);
            daccB = __builtin_amdgcn_mfma_f32_16x16x32_bf16(ones8, paB[kv], daccB, 0, 0, 0);
            #pragma unroll
            for (int vm = 0; vm < 4; ++vm) {
                const bf16x8 vf = *(const bf16x8*)&Vt[buf][(vm * 16 + c) * 64 + (((kv * 4 + g) ^ vswz[vm]) * 8)];
                oA[vm] = __builtin_amdgcn_mfma_f32_16x16x32_bf16(vf, paA[kv], oA[vm], 0, 0, 0);
                oB[vm] = __builtin_amdgcn_mfma_f32_16x16x32_bf16(vf, paB[kv], oB[vm], 0, 0, 0);
            }
        }
        __builtin_amdgcn_s_setprio(0);

        __syncthreads();
    }

    const float invA = 1.0f / daccA[0];
    const float invB = 1.0f / daccB[0];

    #pragma unroll
    for (int vm = 0; vm < 4; ++vm) {
        f32x4 vA, vB;
        #pragma unroll
        for (int r = 0; r < 4; ++r) { vA[r] = oA[vm][r] * invA; vB[r] = oB[vm][r] * invB; }
        bf16x4 pA = __builtin_convertvector(vA, bf16x4);
        bf16x4 pB = __builtin_convertvector(vB, bf16x4);
        *(bf16x4*)(attnb + (size_t)(b * 2048 + tA) * 1024 + h * 64 + vm * 16 + g * 4) = pA;
        *(bf16x4*)(attnb + (size_t)(b * 2048 + tB) * 1024 + h * 64 + vm * 16 + g * 4) = pB;
    }
}

// ---------------------------------------------------------------------------
// Workspace layout (WkT||WvT||WqT contiguous for merged K|V|Q):
//   [0..2)   WkT   [2..4) WvT   [4..6) WqT   [6..8) WoT   [8..9) flagsB
//   [9..25)  VCONV   [25..41) QCONV (-> attnb)   [41..57) Kp   [57..73) VTp
//   [73..89) Qp (merged path only; fallback aliases Qp = VCONV)
// ---------------------------------------------------------------------------
extern "C" void kernel_launch(void* const* d_in, const int* in_sizes, int n_in,
                              void* d_out, int out_size, void* d_ws, size_t ws_size,
                              hipStream_t stream) {
    const float* query = (const float*)d_in[0];
    const float* value = (const float*)d_in[1];
    const int*   mask  = (const int*)d_in[2];
    const float* Wq = (const float*)d_in[3];
    const float* bq = (const float*)d_in[4];
    const float* Wk = (const float*)d_in[5];
    const float* bk = (const float*)d_in[6];
    const float* Wv = (const float*)d_in[7];
    const float* bv = (const float*)d_in[8];
    const float* Wo = (const float*)d_in[9];
    const float* bo = (const float*)d_in[10];

    char* ws = (char*)d_ws;
    unsigned short* WkT   = (unsigned short*)(ws + ((size_t)0  << 20));
    unsigned short* WvT   = (unsigned short*)(ws + ((size_t)2  << 20));
    unsigned short* WqT   = (unsigned short*)(ws + ((size_t)4  << 20));
    unsigned short* WoT   = (unsigned short*)(ws + ((size_t)6  << 20));
    unsigned char*  flagsB= (unsigned char*) (ws + ((size_t)8  << 20));
    unsigned short* VCONV = (unsigned short*)(ws + ((size_t)9  << 20));
    unsigned short* QCONV = (unsigned short*)(ws + ((size_t)25 << 20));
    unsigned short* Kp    = (unsigned short*)(ws + ((size_t)41 << 20));
    unsigned short* VTp   = (unsigned short*)(ws + ((size_t)57 << 20));

    const bool merged = ws_size >= ((size_t)90 << 20);
    unsigned short* Qp    = merged ? (unsigned short*)(ws + ((size_t)73 << 20)) : VCONV;
    unsigned short* attnb = QCONV;

    prepass_kernel<<<5120, 256, 0, stream>>>(value, VCONV, query, QCONV,
                                             Wq, Wk, Wv, Wo, WqT, WkT, WvT, WoT,
                                             mask, flagsB);

    if (merged) {
        mm_kernel<4, 24><<<1536, 256, 0, stream>>>(VCONV, QCONV, WkT, bk, bv, bq,
                                                   1.0f, Kp, VTp, Qp);
    } else {
        mm_kernel<3, 16><<<1024, 256, 0, stream>>>(VCONV, nullptr, WkT, bk, bv, bq,
                                                   1.0f, Kp, VTp, nullptr);
        mm_kernel<0, 8><<<512, 256, 0, stream>>>(QCONV, nullptr, WqT, bq, bq, bq,
                                                 C_EXP, Qp, nullptr, nullptr);
    }

    attn_kernel<<<1024, 256, 0, stream>>>(Qp, Kp, VTp, mask, flagsB, attnb);

    mm_kernel<2, 8><<<512, 256, 0, stream>>>(attnb, nullptr, WoT, bo, bo, bo,
                                             1.0f, d_out, nullptr, nullptr);
}